// Round 1
// baseline (1232.184 us; speedup 1.0000x reference)
//
#include <hip/hip_runtime.h>

#define BLOCK 256

// ---------------- kernels ----------------

__global__ void init_deg_kernel(float* __restrict__ deg, int nN) {
    int n = blockIdx.x * blockDim.x + threadIdx.x;
    if (n < nN) deg[n] = 1.0f;            // self-loop weight
}

__global__ void scatter_deg_kernel(const int* __restrict__ col,
                                   const float* __restrict__ w,
                                   float* __restrict__ deg, int nE) {
    int e = blockIdx.x * blockDim.x + threadIdx.x;
    if (e < nE) atomicAdd(&deg[col[e]], w[e]);
}

__global__ void dinv_kernel(float* __restrict__ deg, int nN) {
    int n = blockIdx.x * blockDim.x + threadIdx.x;
    if (n < nN) {
        float d = deg[n];
        deg[n] = (d > 0.0f) ? rsqrtf(d) : 0.0f;   // d >= 1 always, guard for exactness
    }
}

__global__ void norm_kernel(const int* __restrict__ row, const int* __restrict__ col,
                            const float* __restrict__ w, const float* __restrict__ dinv,
                            float* __restrict__ norm, int nE) {
    int e = blockIdx.x * blockDim.x + threadIdx.x;
    if (e < nE) norm[e] = dinv[row[e]] * w[e] * dinv[col[e]];
}

// t[n][j] = sum_k x[n][k] * W[k][j],  K=4, out=32
__global__ void gemm_k4(const float* __restrict__ x, const float* __restrict__ W,
                        float* __restrict__ t, int nN) {
    __shared__ float Ws[4 * 32];
    for (int i = threadIdx.x; i < 4 * 32; i += blockDim.x) Ws[i] = W[i];
    __syncthreads();
    long long tid = (long long)blockIdx.x * blockDim.x + threadIdx.x;
    int n = (int)(tid >> 5), j = (int)(tid & 31);
    if (n >= nN) return;
    const float* xn = x + (long long)n * 4;
    float acc = 0.0f;
#pragma unroll
    for (int k = 0; k < 4; ++k) acc += xn[k] * Ws[k * 32 + j];
    t[(long long)n * 32 + j] = acc;
}

// t[n][j] = sum_k h[n][k] * W[k][j],  K=32, out=32
__global__ void gemm_k32(const float* __restrict__ h, const float* __restrict__ W,
                         float* __restrict__ t, int nN) {
    __shared__ float Ws[32 * 32];
    for (int i = threadIdx.x; i < 32 * 32; i += blockDim.x) Ws[i] = W[i];
    __syncthreads();
    long long tid = (long long)blockIdx.x * blockDim.x + threadIdx.x;
    int n = (int)(tid >> 5), j = (int)(tid & 31);
    if (n >= nN) return;
    const float* hn = h + (long long)n * 32;
    float acc = 0.0f;
#pragma unroll
    for (int k = 0; k < 32; ++k) acc += hn[k] * Ws[k * 32 + j];
    t[(long long)n * 32 + j] = acc;
}

// agg[n][f] = dinv[n]^2 * t[n][f]   (self-loop contribution; also initializes agg)
__global__ void init_agg_kernel(const float* __restrict__ t, const float* __restrict__ dinv,
                                float* __restrict__ agg, int nN) {
    long long tid = (long long)blockIdx.x * blockDim.x + threadIdx.x;
    int n = (int)(tid >> 5), f = (int)(tid & 31);
    if (n >= nN) return;
    float di = dinv[n];
    agg[(long long)n * 32 + f] = di * di * t[(long long)n * 32 + f];
}

// agg[col[e]][f] += norm[e] * t[row[e]][f]
__global__ void scatter_edges_kernel(const int* __restrict__ row, const int* __restrict__ col,
                                     const float* __restrict__ norm, const float* __restrict__ t,
                                     float* __restrict__ agg, int nE) {
    long long tid = (long long)blockIdx.x * blockDim.x + threadIdx.x;
    long long e = tid >> 5;
    int f = (int)(tid & 31);
    if (e >= nE) return;
    int r = row[e], c = col[e];
    float v = norm[e] * t[(long long)r * 32 + f];
    atomicAdd(&agg[(long long)c * 32 + f], v);
}

// h[n][f] = (relu?) (agg[n][f] + b[f])
__global__ void epilogue_kernel(const float* __restrict__ agg, const float* __restrict__ b,
                                float* __restrict__ h, int nN, int doRelu) {
    long long tid = (long long)blockIdx.x * blockDim.x + threadIdx.x;
    int n = (int)(tid >> 5), f = (int)(tid & 31);
    if (n >= nN) return;
    float v = agg[(long long)n * 32 + f] + b[f];
    if (doRelu) v = fmaxf(v, 0.0f);
    h[(long long)n * 32 + f] = v;
}

__global__ void init_pool_kernel(float* __restrict__ sums, float* __restrict__ cnt, int G) {
    int i = blockIdx.x * blockDim.x + threadIdx.x;
    if (i < G * 32) sums[i] = 0.0f;
    if (i < G) cnt[i] = 0.0f;
}

__global__ void pool_kernel(const float* __restrict__ h, const int* __restrict__ batch,
                            float* __restrict__ sums, float* __restrict__ cnt, int nN) {
    long long tid = (long long)blockIdx.x * blockDim.x + threadIdx.x;
    int n = (int)(tid >> 5), f = (int)(tid & 31);
    if (n >= nN) return;
    int g = batch[n];
    atomicAdd(&sums[(long long)g * 32 + f], h[(long long)n * 32 + f]);
    if (f == 0) atomicAdd(&cnt[g], 1.0f);
}

__global__ void final_kernel(const float* __restrict__ sums, const float* __restrict__ cnt,
                             const float* __restrict__ lin_w, const float* __restrict__ lin_b,
                             float* __restrict__ out, int G) {
    int g = blockIdx.x * blockDim.x + threadIdx.x;
    if (g >= G) return;
    float c = fmaxf(cnt[g], 1.0f);
    float inv = 1.0f / c;
    float l0 = lin_b[0], l1 = lin_b[1], l2 = lin_b[2];
#pragma unroll
    for (int f = 0; f < 32; ++f) {
        float m = sums[g * 32 + f] * inv;
        l0 += m * lin_w[f * 3 + 0];
        l1 += m * lin_w[f * 3 + 1];
        l2 += m * lin_w[f * 3 + 2];
    }
    float mx = fmaxf(l0, fmaxf(l1, l2));
    float e0 = expf(l0 - mx), e1 = expf(l1 - mx), e2 = expf(l2 - mx);
    float s = 1.0f / (e0 + e1 + e2);
    out[g * 3 + 0] = e0 * s;
    out[g * 3 + 1] = e1 * s;
    out[g * 3 + 2] = e2 * s;
}

// ---------------- launch ----------------

extern "C" void kernel_launch(void* const* d_in, const int* in_sizes, int n_in,
                              void* d_out, int out_size, void* d_ws, size_t ws_size,
                              hipStream_t stream) {
    const float* x       = (const float*)d_in[0];
    const int*   ei      = (const int*)d_in[1];
    const float* ew      = (const float*)d_in[2];
    const int*   batch   = (const int*)d_in[3];
    const float* W1      = (const float*)d_in[4];
    const float* b1      = (const float*)d_in[5];
    const float* W2      = (const float*)d_in[6];
    const float* b2      = (const float*)d_in[7];
    const float* W3      = (const float*)d_in[8];
    const float* b3      = (const float*)d_in[9];
    const float* lin_w   = (const float*)d_in[10];
    const float* lin_b   = (const float*)d_in[11];
    float* out = (float*)d_out;

    const int nN = in_sizes[0] / 4;       // 100000
    const int nE = in_sizes[2];           // 2500000
    const int G  = out_size / 3;          // 1000
    const int* row = ei;                  // edge_index[0]
    const int* col = ei + nE;             // edge_index[1]

    // workspace layout (floats)
    float* ws    = (float*)d_ws;
    float* dinv  = ws;                                   // [nN]
    float* norm  = dinv + nN;                            // [nE]
    float* bufA  = norm + nE;                            // [nN*32]
    float* bufB  = bufA + (long long)nN * 32;            // [nN*32]
    float* bufC  = bufB + (long long)nN * 32;            // [nN*32]
    float* sums  = bufC + (long long)nN * 32;            // [G*32]
    float* cnt   = sums + (long long)G * 32;             // [G]

    const long long nf = (long long)nN * 32;
    const long long ef = (long long)nE * 32;
    const int gN   = (nN + BLOCK - 1) / BLOCK;
    const int gE   = (nE + BLOCK - 1) / BLOCK;
    const int gNF  = (int)((nf + BLOCK - 1) / BLOCK);
    const int gEF  = (int)((ef + BLOCK - 1) / BLOCK);

    // normalization
    init_deg_kernel<<<gN, BLOCK, 0, stream>>>(dinv, nN);
    scatter_deg_kernel<<<gE, BLOCK, 0, stream>>>(col, ew, dinv, nE);
    dinv_kernel<<<gN, BLOCK, 0, stream>>>(dinv, nN);
    norm_kernel<<<gE, BLOCK, 0, stream>>>(row, col, ew, dinv, norm, nE);

    // layer 1: x[N,4] @ W1 -> relu
    gemm_k4<<<gNF, BLOCK, 0, stream>>>(x, W1, bufB, nN);
    init_agg_kernel<<<gNF, BLOCK, 0, stream>>>(bufB, dinv, bufC, nN);
    scatter_edges_kernel<<<gEF, BLOCK, 0, stream>>>(row, col, norm, bufB, bufC, nE);
    epilogue_kernel<<<gNF, BLOCK, 0, stream>>>(bufC, b1, bufA, nN, 1);

    // layer 2
    gemm_k32<<<gNF, BLOCK, 0, stream>>>(bufA, W2, bufB, nN);
    init_agg_kernel<<<gNF, BLOCK, 0, stream>>>(bufB, dinv, bufC, nN);
    scatter_edges_kernel<<<gEF, BLOCK, 0, stream>>>(row, col, norm, bufB, bufC, nE);
    epilogue_kernel<<<gNF, BLOCK, 0, stream>>>(bufC, b2, bufA, nN, 1);

    // layer 3 (no relu)
    gemm_k32<<<gNF, BLOCK, 0, stream>>>(bufA, W3, bufB, nN);
    init_agg_kernel<<<gNF, BLOCK, 0, stream>>>(bufB, dinv, bufC, nN);
    scatter_edges_kernel<<<gEF, BLOCK, 0, stream>>>(row, col, norm, bufB, bufC, nE);
    epilogue_kernel<<<gNF, BLOCK, 0, stream>>>(bufC, b3, bufA, nN, 0);

    // pooling + classifier
    const int gG = (G * 32 + BLOCK - 1) / BLOCK;
    init_pool_kernel<<<gG, BLOCK, 0, stream>>>(sums, cnt, G);
    pool_kernel<<<gNF, BLOCK, 0, stream>>>(bufA, batch, sums, cnt, nN);
    final_kernel<<<(G + BLOCK - 1) / BLOCK, BLOCK, 0, stream>>>(sums, cnt, lin_w, lin_b, out, G);
}

// Round 2
// 878.512 us; speedup vs baseline: 1.4026x; 1.4026x over previous
//
#include <hip/hip_runtime.h>

#define BLOCK 256

// ---------------- setup kernels ----------------

__global__ void init_kernel(float* __restrict__ deg, int* __restrict__ ecnt,
                            float* __restrict__ sums, float* __restrict__ cnt,
                            int nN, int G) {
    int i = blockIdx.x * BLOCK + threadIdx.x;
    if (i < nN) { deg[i] = 1.0f; ecnt[i] = 0; }   // deg starts at self-loop weight
    if (i < G * 32) sums[i] = 0.0f;
    if (i < G) cnt[i] = 0.0f;
}

__global__ void hist_kernel(const int* __restrict__ col, const float* __restrict__ w,
                            float* __restrict__ deg, int* __restrict__ ecnt, int nE) {
    int e = blockIdx.x * BLOCK + threadIdx.x;
    if (e < nE) {
        int c = col[e];
        atomicAdd(&deg[c], w[e]);
        atomicAdd(&ecnt[c], 1);
    }
}

__global__ void dinv_kernel(float* __restrict__ deg, int nN) {
    int n = blockIdx.x * BLOCK + threadIdx.x;
    if (n < nN) {
        float d = deg[n];
        deg[n] = (d > 0.0f) ? rsqrtf(d) : 0.0f;
    }
}

// ---------------- exclusive scan of ecnt -> rowptr (3 kernels) ----------------

__global__ void scanA_kernel(const int* __restrict__ ecnt, int* __restrict__ blkSum, int nN) {
    __shared__ int s[BLOCK];
    int i = blockIdx.x * BLOCK + threadIdx.x;
    s[threadIdx.x] = (i < nN) ? ecnt[i] : 0;
    __syncthreads();
    for (int off = BLOCK / 2; off > 0; off >>= 1) {
        if (threadIdx.x < off) s[threadIdx.x] += s[threadIdx.x + off];
        __syncthreads();
    }
    if (threadIdx.x == 0) blkSum[blockIdx.x] = s[0];
}

__global__ void scanB_kernel(const int* __restrict__ blkSum, int* __restrict__ blkOff,
                             int* __restrict__ rowptr, int NB, int nN) {
    __shared__ int s[512];
    int t = threadIdx.x;
    s[t] = (t < NB) ? blkSum[t] : 0;
    __syncthreads();
    for (int off = 1; off < 512; off <<= 1) {
        int v = (t >= off) ? s[t - off] : 0;
        __syncthreads();
        s[t] += v;
        __syncthreads();
    }
    if (t < NB) blkOff[t] = (t == 0) ? 0 : s[t - 1];
    if (t == 0) rowptr[nN] = s[511];   // total edge count
}

__global__ void scanC_kernel(const int* __restrict__ ecnt, const int* __restrict__ blkOff,
                             int* __restrict__ rowptr, int* __restrict__ cursor, int nN) {
    __shared__ int s[BLOCK];
    int i = blockIdx.x * BLOCK + threadIdx.x;
    int t = threadIdx.x;
    int v = (i < nN) ? ecnt[i] : 0;
    s[t] = v;
    __syncthreads();
    for (int off = 1; off < BLOCK; off <<= 1) {
        int u = (t >= off) ? s[t - off] : 0;
        __syncthreads();
        s[t] += u;
        __syncthreads();
    }
    int rp = blkOff[blockIdx.x] + s[t] - v;   // exclusive = inclusive - self
    if (i < nN) { rowptr[i] = rp; cursor[i] = rp; }
}

// fill CSR slots: packed (src as float bits, norm) per edge
__global__ void fill_kernel(const int* __restrict__ row, const int* __restrict__ col,
                            const float* __restrict__ w, const float* __restrict__ dinv,
                            int* __restrict__ cursor, float2* __restrict__ csr, int nE) {
    int e = blockIdx.x * BLOCK + threadIdx.x;
    if (e < nE) {
        int r = row[e], c = col[e];
        int pos = atomicAdd(&cursor[c], 1);
        float nrm = dinv[r] * w[e] * dinv[c];
        csr[pos] = make_float2(__int_as_float(r), nrm);
    }
}

// ---------------- t1 = x @ W1  (K=4, out=32) ----------------

__global__ void gemm_k4(const float* __restrict__ x, const float* __restrict__ W,
                        float* __restrict__ t, int nN) {
    __shared__ float Ws[4 * 32];
    for (int i = threadIdx.x; i < 4 * 32; i += blockDim.x) Ws[i] = W[i];
    __syncthreads();
    long long tid = (long long)blockIdx.x * blockDim.x + threadIdx.x;
    int n = (int)(tid >> 5), j = (int)(tid & 31);
    if (n >= nN) return;
    const float* xn = x + (long long)n * 4;
    float acc = 0.0f;
#pragma unroll
    for (int k = 0; k < 4; ++k) acc += xn[k] * Ws[k * 32 + j];
    t[(long long)n * 32 + j] = acc;
}

// ---------------- fused layer pass ----------------
// Aggregates t over incoming edges (CSR gather, no atomics) + self loop,
// adds bias, then either (a) relu + GEMM with next layer's W -> t_next,
// or (b) LAST: pools into sums/cnt.

template <bool LAST>
__global__ void layer_pass(const float* __restrict__ t, const int* __restrict__ rowptr,
                           const float2* __restrict__ csr, const float* __restrict__ dinv,
                           const float* __restrict__ b, const float* __restrict__ W,
                           float* __restrict__ t_next,
                           const int* __restrict__ batch, float* __restrict__ sums,
                           float* __restrict__ cnt, int nN) {
    __shared__ float Ws[32 * 32];
    __shared__ float hS[BLOCK / 32][32];
    if (!LAST) {
        for (int i = threadIdx.x; i < 32 * 32; i += BLOCK) Ws[i] = W[i];
    }
    int tid = blockIdx.x * BLOCK + threadIdx.x;
    int n = tid >> 5, f = tid & 31;
    bool act = n < nN;
    float h = 0.0f;
    if (act) {
        float di = dinv[n];
        int s0 = rowptr[n], s1 = rowptr[n + 1];
        float acc = di * di * t[(size_t)n * 32 + f];
        int j = s0;
        for (; j + 1 < s1; j += 2) {
            float2 p0 = csr[j];
            float2 p1 = csr[j + 1];
            acc = fmaf(p0.y, t[(size_t)__float_as_int(p0.x) * 32 + f], acc);
            acc = fmaf(p1.y, t[(size_t)__float_as_int(p1.x) * 32 + f], acc);
        }
        if (j < s1) {
            float2 p = csr[j];
            acc = fmaf(p.y, t[(size_t)__float_as_int(p.x) * 32 + f], acc);
        }
        h = acc + b[f];
        if (!LAST) h = fmaxf(h, 0.0f);
    }
    if (LAST) {
        if (act) {
            int g = batch[n];
            atomicAdd(&sums[(size_t)g * 32 + f], h);
            if (f == 0) atomicAdd(&cnt[g], 1.0f);
        }
    } else {
        int half = threadIdx.x >> 5;
        hS[half][f] = h;
        __syncthreads();
        if (act) {
            float a2 = 0.0f;
#pragma unroll
            for (int k = 0; k < 32; ++k) a2 = fmaf(hS[half][k], Ws[k * 32 + f], a2);
            t_next[(size_t)n * 32 + f] = a2;
        }
    }
}

// ---------------- classifier ----------------

__global__ void final_kernel(const float* __restrict__ sums, const float* __restrict__ cnt,
                             const float* __restrict__ lin_w, const float* __restrict__ lin_b,
                             float* __restrict__ out, int G) {
    int g = blockIdx.x * blockDim.x + threadIdx.x;
    if (g >= G) return;
    float c = fmaxf(cnt[g], 1.0f);
    float inv = 1.0f / c;
    float l0 = lin_b[0], l1 = lin_b[1], l2 = lin_b[2];
#pragma unroll
    for (int f = 0; f < 32; ++f) {
        float m = sums[g * 32 + f] * inv;
        l0 = fmaf(m, lin_w[f * 3 + 0], l0);
        l1 = fmaf(m, lin_w[f * 3 + 1], l1);
        l2 = fmaf(m, lin_w[f * 3 + 2], l2);
    }
    float mx = fmaxf(l0, fmaxf(l1, l2));
    float e0 = expf(l0 - mx), e1 = expf(l1 - mx), e2 = expf(l2 - mx);
    float s = 1.0f / (e0 + e1 + e2);
    out[g * 3 + 0] = e0 * s;
    out[g * 3 + 1] = e1 * s;
    out[g * 3 + 2] = e2 * s;
}

// ---------------- launch ----------------

extern "C" void kernel_launch(void* const* d_in, const int* in_sizes, int n_in,
                              void* d_out, int out_size, void* d_ws, size_t ws_size,
                              hipStream_t stream) {
    const float* x     = (const float*)d_in[0];
    const int*   ei    = (const int*)d_in[1];
    const float* ew    = (const float*)d_in[2];
    const int*   batch = (const int*)d_in[3];
    const float* W1    = (const float*)d_in[4];
    const float* b1    = (const float*)d_in[5];
    const float* W2    = (const float*)d_in[6];
    const float* b2    = (const float*)d_in[7];
    const float* W3    = (const float*)d_in[8];
    const float* b3    = (const float*)d_in[9];
    const float* lin_w = (const float*)d_in[10];
    const float* lin_b = (const float*)d_in[11];
    float* out = (float*)d_out;

    const int nN = in_sizes[0] / 4;       // 100000
    const int nE = in_sizes[2];           // 2500000
    const int G  = out_size / 3;          // 1000
    const int* row = ei;
    const int* col = ei + nE;

    const int NB = (nN + BLOCK - 1) / BLOCK;   // scan blocks (391)

    // workspace layout (4-byte units)
    float* ws      = (float*)d_ws;
    float* deg     = ws;                              // [nN] -> becomes dinv in place
    float* sums    = deg + nN;                        // [G*32]
    float* cnt     = sums + (long long)G * 32;        // [G]
    int*   ecnt    = (int*)(cnt + G);                 // [nN]
    int*   rowptr  = ecnt + nN;                       // [nN+1]
    int*   cursor  = rowptr + nN + 1;                 // [nN]
    int*   blkSum  = cursor + nN;                     // [512]
    int*   blkOff  = blkSum + 512;                    // [512]
    float2* csr    = (float2*)(blkOff + 512);         // [nE] packed (src, norm)
    float* t_a     = (float*)(csr + nE);              // [nN*32]
    float* t_b     = t_a + (long long)nN * 32;        // [nN*32]

    const int gN  = (nN + BLOCK - 1) / BLOCK;
    const int gE  = (nE + BLOCK - 1) / BLOCK;
    const int gNF = (int)(((long long)nN * 32 + BLOCK - 1) / BLOCK);

    // ---- graph normalization + CSR build ----
    init_kernel<<<gN, BLOCK, 0, stream>>>(deg, ecnt, sums, cnt, nN, G);
    hist_kernel<<<gE, BLOCK, 0, stream>>>(col, ew, deg, ecnt, nE);
    dinv_kernel<<<gN, BLOCK, 0, stream>>>(deg, nN);
    scanA_kernel<<<NB, BLOCK, 0, stream>>>(ecnt, blkSum, nN);
    scanB_kernel<<<1, 512, 0, stream>>>(blkSum, blkOff, rowptr, NB, nN);
    scanC_kernel<<<NB, BLOCK, 0, stream>>>(ecnt, blkOff, rowptr, cursor, nN);
    fill_kernel<<<gE, BLOCK, 0, stream>>>(row, col, ew, deg, cursor, csr, nE);

    // ---- layers ----
    gemm_k4<<<gNF, BLOCK, 0, stream>>>(x, W1, t_a, nN);
    // layer1: agg(t_a) + b1, relu, @W2 -> t_b
    layer_pass<false><<<gNF, BLOCK, 0, stream>>>(t_a, rowptr, csr, deg, b1, W2, t_b,
                                                 nullptr, nullptr, nullptr, nN);
    // layer2: agg(t_b) + b2, relu, @W3 -> t_a
    layer_pass<false><<<gNF, BLOCK, 0, stream>>>(t_b, rowptr, csr, deg, b2, W3, t_a,
                                                 nullptr, nullptr, nullptr, nN);
    // layer3: agg(t_a) + b3, pool
    layer_pass<true><<<gNF, BLOCK, 0, stream>>>(t_a, rowptr, csr, deg, b3, nullptr, nullptr,
                                                batch, sums, cnt, nN);

    final_kernel<<<(G + BLOCK - 1) / BLOCK, BLOCK, 0, stream>>>(sums, cnt, lin_w, lin_b, out, G);
}

// Round 3
// 852.142 us; speedup vs baseline: 1.4460x; 1.0309x over previous
//
#include <hip/hip_runtime.h>

#define BLOCK 256

// ---------------- setup kernels ----------------

__global__ void init_kernel(float* __restrict__ deg, int* __restrict__ ecnt,
                            float* __restrict__ sums, float* __restrict__ cnt,
                            int nN, int G) {
    int i = blockIdx.x * BLOCK + threadIdx.x;
    if (i < nN) { deg[i] = 1.0f; ecnt[i] = 0; }   // deg starts at self-loop weight
    if (i < G * 32) sums[i] = 0.0f;
    if (i < G) cnt[i] = 0.0f;
}

__global__ void hist_kernel(const int* __restrict__ col, const float* __restrict__ w,
                            float* __restrict__ deg, int* __restrict__ ecnt, int nE) {
    int e = blockIdx.x * BLOCK + threadIdx.x;
    if (e < nE) {
        int c = col[e];
        atomicAdd(&deg[c], w[e]);
        atomicAdd(&ecnt[c], 1);
    }
}

__global__ void dinv_kernel(float* __restrict__ deg, int nN) {
    int n = blockIdx.x * BLOCK + threadIdx.x;
    if (n < nN) {
        float d = deg[n];
        deg[n] = (d > 0.0f) ? rsqrtf(d) : 0.0f;
    }
}

// ---------------- exclusive scan of ecnt -> rowptr ----------------

__global__ void scanA_kernel(const int* __restrict__ ecnt, int* __restrict__ blkSum, int nN) {
    __shared__ int s[BLOCK];
    int i = blockIdx.x * BLOCK + threadIdx.x;
    s[threadIdx.x] = (i < nN) ? ecnt[i] : 0;
    __syncthreads();
    for (int off = BLOCK / 2; off > 0; off >>= 1) {
        if (threadIdx.x < off) s[threadIdx.x] += s[threadIdx.x + off];
        __syncthreads();
    }
    if (threadIdx.x == 0) blkSum[blockIdx.x] = s[0];
}

__global__ void scanB_kernel(const int* __restrict__ blkSum, int* __restrict__ blkOff,
                             int* __restrict__ rowptr, int NB, int nN) {
    __shared__ int s[512];
    int t = threadIdx.x;
    s[t] = (t < NB) ? blkSum[t] : 0;
    __syncthreads();
    for (int off = 1; off < 512; off <<= 1) {
        int v = (t >= off) ? s[t - off] : 0;
        __syncthreads();
        s[t] += v;
        __syncthreads();
    }
    if (t < NB) blkOff[t] = (t == 0) ? 0 : s[t - 1];
    if (t == 0) rowptr[nN] = s[511];
}

__global__ void scanC_kernel(const int* __restrict__ ecnt, const int* __restrict__ blkOff,
                             int* __restrict__ rowptr, int* __restrict__ cursor, int nN) {
    __shared__ int s[BLOCK];
    int i = blockIdx.x * BLOCK + threadIdx.x;
    int t = threadIdx.x;
    int v = (i < nN) ? ecnt[i] : 0;
    s[t] = v;
    __syncthreads();
    for (int off = 1; off < BLOCK; off <<= 1) {
        int u = (t >= off) ? s[t - off] : 0;
        __syncthreads();
        s[t] += u;
        __syncthreads();
    }
    int rp = blkOff[blockIdx.x] + s[t] - v;
    if (i < nN) { rowptr[i] = rp; cursor[i] = rp; }
}

__global__ void fill_kernel(const int* __restrict__ row, const int* __restrict__ col,
                            const float* __restrict__ w, const float* __restrict__ dinv,
                            int* __restrict__ cursor, float2* __restrict__ csr, int nE) {
    int e = blockIdx.x * BLOCK + threadIdx.x;
    if (e < nE) {
        int r = row[e], c = col[e];
        int pos = atomicAdd(&cursor[c], 1);
        float nrm = dinv[r] * w[e] * dinv[c];
        csr[pos] = make_float2(__int_as_float(r), nrm);
    }
}

// ---------------- t1 = x @ W1  (K=4, out=32) ----------------

__global__ void gemm_k4(const float* __restrict__ x, const float* __restrict__ W,
                        float* __restrict__ t, int nN) {
    __shared__ float Ws[4 * 32];
    for (int i = threadIdx.x; i < 4 * 32; i += blockDim.x) Ws[i] = W[i];
    __syncthreads();
    long long tid = (long long)blockIdx.x * blockDim.x + threadIdx.x;
    int n = (int)(tid >> 5), j = (int)(tid & 31);
    if (n >= nN) return;
    const float* xn = x + (long long)n * 4;
    float acc = 0.0f;
#pragma unroll
    for (int k = 0; k < 4; ++k) acc += xn[k] * Ws[k * 32 + j];
    t[(long long)n * 32 + j] = acc;
}

// ---------------- fused layer pass: one node per 64-lane wave ----------------
// lane = e2*32 + f : half-waves process even/odd edges of the SAME node.
// Batches of 16 edges keep 16 random gather lines in flight per wave.

template <bool LAST>
__global__ void layer_pass(const float* __restrict__ t, const int* __restrict__ rowptr,
                           const float2* __restrict__ csr, const float* __restrict__ dinv,
                           const float* __restrict__ b, const float* __restrict__ W,
                           float* __restrict__ t_next,
                           const int* __restrict__ batch, float* __restrict__ sums,
                           float* __restrict__ cnt, int nN) {
    __shared__ float Ws[32 * 32];
    __shared__ float hS[BLOCK / 64][32];
    if (!LAST) {
        for (int i = threadIdx.x; i < 32 * 32; i += BLOCK) Ws[i] = W[i];
        __syncthreads();   // Ws is shared across waves; hS below is wave-private
    }
    int wv   = threadIdx.x >> 6;                 // wave id in block
    int lane = threadIdx.x & 63;
    int e2   = lane >> 5;                        // 0/1: which edge of each pair
    int f    = lane & 31;                        // feature
    int n    = blockIdx.x * (BLOCK / 64) + wv;   // node id (wave-uniform)
    if (n >= nN) return;                         // whole-wave uniform exit

    float di = dinv[n];
    int s0 = rowptr[n], s1 = rowptr[n + 1];
    float acc = (e2 == 0) ? di * di * t[(size_t)n * 32 + f] : 0.0f;

    int j4 = s0;
    for (; j4 + 16 <= s1; j4 += 16) {            // 16 edges in flight per wave
        float2 p[8]; float v[8];
#pragma unroll
        for (int u = 0; u < 8; ++u) p[u] = csr[j4 + 2 * u + e2];
#pragma unroll
        for (int u = 0; u < 8; ++u) v[u] = t[(size_t)__float_as_int(p[u].x) * 32 + f];
#pragma unroll
        for (int u = 0; u < 8; ++u) acc = fmaf(p[u].y, v[u], acc);
    }
    for (; j4 + 4 <= s1; j4 += 4) {              // 4 edges in flight
        float2 p[2]; float v[2];
#pragma unroll
        for (int u = 0; u < 2; ++u) p[u] = csr[j4 + 2 * u + e2];
#pragma unroll
        for (int u = 0; u < 2; ++u) v[u] = t[(size_t)__float_as_int(p[u].x) * 32 + f];
#pragma unroll
        for (int u = 0; u < 2; ++u) acc = fmaf(p[u].y, v[u], acc);
    }
    for (int j = j4 + e2; j < s1; j += 2) {      // tail (<4 edges)
        float2 p = csr[j];
        acc = fmaf(p.y, t[(size_t)__float_as_int(p.x) * 32 + f], acc);
    }

    acc += __shfl_xor(acc, 32);                  // cross-half reduce (both halves get sum)
    float h = acc + b[f];

    if (LAST) {
        if (lane < 32) {
            int g = batch[n];
            atomicAdd(&sums[(size_t)g * 32 + f], h);
            if (f == 0) atomicAdd(&cnt[g], 1.0f);
        }
    } else {
        h = fmaxf(h, 0.0f);
        if (lane < 32) hS[wv][f] = h;            // wave-private slice; DS ops are in-order
        float a2 = 0.0f;
#pragma unroll
        for (int k = 0; k < 16; ++k) {           // split-k across the two halves
            int kk = e2 * 16 + k;
            a2 = fmaf(hS[wv][kk], Ws[kk * 32 + f], a2);
        }
        a2 += __shfl_xor(a2, 32);
        if (lane < 32) t_next[(size_t)n * 32 + f] = a2;
    }
}

// ---------------- classifier ----------------

__global__ void final_kernel(const float* __restrict__ sums, const float* __restrict__ cnt,
                             const float* __restrict__ lin_w, const float* __restrict__ lin_b,
                             float* __restrict__ out, int G) {
    int g = blockIdx.x * blockDim.x + threadIdx.x;
    if (g >= G) return;
    float c = fmaxf(cnt[g], 1.0f);
    float inv = 1.0f / c;
    float l0 = lin_b[0], l1 = lin_b[1], l2 = lin_b[2];
#pragma unroll
    for (int f = 0; f < 32; ++f) {
        float m = sums[g * 32 + f] * inv;
        l0 = fmaf(m, lin_w[f * 3 + 0], l0);
        l1 = fmaf(m, lin_w[f * 3 + 1], l1);
        l2 = fmaf(m, lin_w[f * 3 + 2], l2);
    }
    float mx = fmaxf(l0, fmaxf(l1, l2));
    float e0 = expf(l0 - mx), e1 = expf(l1 - mx), e2 = expf(l2 - mx);
    float s = 1.0f / (e0 + e1 + e2);
    out[g * 3 + 0] = e0 * s;
    out[g * 3 + 1] = e1 * s;
    out[g * 3 + 2] = e2 * s;
}

// ---------------- launch ----------------

extern "C" void kernel_launch(void* const* d_in, const int* in_sizes, int n_in,
                              void* d_out, int out_size, void* d_ws, size_t ws_size,
                              hipStream_t stream) {
    const float* x     = (const float*)d_in[0];
    const int*   ei    = (const int*)d_in[1];
    const float* ew    = (const float*)d_in[2];
    const int*   batch = (const int*)d_in[3];
    const float* W1    = (const float*)d_in[4];
    const float* b1    = (const float*)d_in[5];
    const float* W2    = (const float*)d_in[6];
    const float* b2    = (const float*)d_in[7];
    const float* W3    = (const float*)d_in[8];
    const float* b3    = (const float*)d_in[9];
    const float* lin_w = (const float*)d_in[10];
    const float* lin_b = (const float*)d_in[11];
    float* out = (float*)d_out;

    const int nN = in_sizes[0] / 4;       // 100000
    const int nE = in_sizes[2];           // 2500000
    const int G  = out_size / 3;          // 1000
    const int* row = ei;
    const int* col = ei + nE;

    const int NB = (nN + BLOCK - 1) / BLOCK;

    // workspace layout (4-byte units)
    float* ws      = (float*)d_ws;
    float* deg     = ws;                              // [nN] -> dinv in place
    float* sums    = deg + nN;                        // [G*32]
    float* cnt     = sums + (long long)G * 32;        // [G]
    int*   ecnt    = (int*)(cnt + G);                 // [nN]
    int*   rowptr  = ecnt + nN;                       // [nN+1]
    int*   cursor  = rowptr + nN + 1;                 // [nN]
    int*   blkSum  = cursor + nN;                     // [512]
    int*   blkOff  = blkSum + 512;                    // [512]
    float2* csr    = (float2*)(blkOff + 512);         // [nE]
    float* t_a     = (float*)(csr + nE);              // [nN*32]
    float* t_b     = t_a + (long long)nN * 32;        // [nN*32]

    const int gN  = (nN + BLOCK - 1) / BLOCK;
    const int gE  = (nE + BLOCK - 1) / BLOCK;
    const int gNF = (int)(((long long)nN * 32 + BLOCK - 1) / BLOCK);
    const int gW  = (nN + (BLOCK / 64) - 1) / (BLOCK / 64);   // one wave per node

    // ---- graph normalization + CSR build ----
    init_kernel<<<gN, BLOCK, 0, stream>>>(deg, ecnt, sums, cnt, nN, G);
    hist_kernel<<<gE, BLOCK, 0, stream>>>(col, ew, deg, ecnt, nE);
    dinv_kernel<<<gN, BLOCK, 0, stream>>>(deg, nN);
    scanA_kernel<<<NB, BLOCK, 0, stream>>>(ecnt, blkSum, nN);
    scanB_kernel<<<1, 512, 0, stream>>>(blkSum, blkOff, rowptr, NB, nN);
    scanC_kernel<<<NB, BLOCK, 0, stream>>>(ecnt, blkOff, rowptr, cursor, nN);
    fill_kernel<<<gE, BLOCK, 0, stream>>>(row, col, ew, deg, cursor, csr, nE);

    // ---- layers ----
    gemm_k4<<<gNF, BLOCK, 0, stream>>>(x, W1, t_a, nN);
    layer_pass<false><<<gW, BLOCK, 0, stream>>>(t_a, rowptr, csr, deg, b1, W2, t_b,
                                                nullptr, nullptr, nullptr, nN);
    layer_pass<false><<<gW, BLOCK, 0, stream>>>(t_b, rowptr, csr, deg, b2, W3, t_a,
                                                nullptr, nullptr, nullptr, nN);
    layer_pass<true><<<gW, BLOCK, 0, stream>>>(t_a, rowptr, csr, deg, b3, nullptr, nullptr,
                                               batch, sums, cnt, nN);

    final_kernel<<<(G + BLOCK - 1) / BLOCK, BLOCK, 0, stream>>>(sums, cnt, lin_w, lin_b, out, G);
}

// Round 4
// 480.269 us; speedup vs baseline: 2.5656x; 1.7743x over previous
//
#include <hip/hip_runtime.h>
#include <hip/hip_fp16.h>

typedef unsigned long long ull;
#define BLOCK 256

// ---------------- setup ----------------

__global__ void init_kernel(ull* __restrict__ packed, float* __restrict__ sums,
                            float* __restrict__ cnt, int nN, int G) {
    int i = blockIdx.x * BLOCK + threadIdx.x;
    if (i < nN) packed[i] = 0ULL;
    if (i < G * 32) sums[i] = 0.0f;
    if (i < G) cnt[i] = 0.0f;
}

// ONE 64-bit atomic per edge: high 12 bits count, low 52 bits fixed-point(2^32) weight sum.
// Returned old value's count = this edge's rank within its destination row.
__global__ void passA_kernel(const int* __restrict__ col, const float* __restrict__ w,
                             ull* __restrict__ packed, int* __restrict__ tmp, int nE) {
    int e = blockIdx.x * BLOCK + threadIdx.x;
    if (e < nE) {
        int c = col[e];
        ull inc = (1ULL << 52) | (ull)((double)w[e] * 4294967296.0);
        ull old = atomicAdd(&packed[c], inc);
        tmp[e] = (int)(old >> 52);
    }
}

__global__ void unpack_kernel(const ull* __restrict__ packed, int* __restrict__ ecnt,
                              float* __restrict__ dinv, int nN) {
    int n = blockIdx.x * BLOCK + threadIdx.x;
    if (n < nN) {
        ull p = packed[n];
        ecnt[n] = (int)(p >> 52);
        float deg = 1.0f + (float)((double)(p & ((1ULL << 52) - 1)) * (1.0 / 4294967296.0));
        dinv[n] = rsqrtf(deg);   // deg >= 1 always
    }
}

// ---------------- exclusive scan of ecnt -> rowptr ----------------

__global__ void scanA_kernel(const int* __restrict__ ecnt, int* __restrict__ blkSum, int nN) {
    __shared__ int s[BLOCK];
    int i = blockIdx.x * BLOCK + threadIdx.x;
    s[threadIdx.x] = (i < nN) ? ecnt[i] : 0;
    __syncthreads();
    for (int off = BLOCK / 2; off > 0; off >>= 1) {
        if (threadIdx.x < off) s[threadIdx.x] += s[threadIdx.x + off];
        __syncthreads();
    }
    if (threadIdx.x == 0) blkSum[blockIdx.x] = s[0];
}

__global__ void scanB_kernel(const int* __restrict__ blkSum, int* __restrict__ blkOff,
                             int* __restrict__ rowptr, int NB, int nN) {
    __shared__ int s[512];
    int t = threadIdx.x;
    s[t] = (t < NB) ? blkSum[t] : 0;
    __syncthreads();
    for (int off = 1; off < 512; off <<= 1) {
        int v = (t >= off) ? s[t - off] : 0;
        __syncthreads();
        s[t] += v;
        __syncthreads();
    }
    if (t < NB) blkOff[t] = (t == 0) ? 0 : s[t - 1];
    if (t == 0) rowptr[nN] = s[511];
}

__global__ void scanC_kernel(const int* __restrict__ ecnt, const int* __restrict__ blkOff,
                             int* __restrict__ rowptr, int nN) {
    __shared__ int s[BLOCK];
    int i = blockIdx.x * BLOCK + threadIdx.x;
    int t = threadIdx.x;
    int v = (i < nN) ? ecnt[i] : 0;
    s[t] = v;
    __syncthreads();
    for (int off = 1; off < BLOCK; off <<= 1) {
        int u = (t >= off) ? s[t - off] : 0;
        __syncthreads();
        s[t] += u;
        __syncthreads();
    }
    if (i < nN) rowptr[i] = blkOff[blockIdx.x] + s[t] - v;
}

// atomic-free fill: pos = rowptr[dest] + rank; norm computed here (dinv ready).
__global__ void passB_kernel(const int* __restrict__ row, const int* __restrict__ col,
                             const float* __restrict__ w, const int* __restrict__ rowptr,
                             const int* __restrict__ tmp, const float* __restrict__ dinv,
                             float2* __restrict__ csr, int nE) {
    int e = blockIdx.x * BLOCK + threadIdx.x;
    if (e < nE) {
        int r = row[e], c = col[e];
        int pos = rowptr[c] + tmp[e];
        float nrm = dinv[r] * w[e] * dinv[c];
        csr[pos] = make_float2(__int_as_float(r), nrm);
    }
}

// ---------------- layer 1: agg(x) @ W1 (linearity) + relu + @W2 -> t2 fp16 ----------------
// One node per wave; lane = edge_slot*4 + component. x table is 1.6MB -> L2-resident.

__global__ void layer1_pass(const float* __restrict__ x, const int* __restrict__ rowptr,
                            const float2* __restrict__ csr, const float* __restrict__ dinv,
                            const float* __restrict__ W1, const float* __restrict__ b1,
                            const float* __restrict__ W2, __half* __restrict__ t_next, int nN) {
    __shared__ float W1s[4 * 32];
    __shared__ float W2s[32 * 32];
    __shared__ float b1s[32];
    __shared__ float hS[BLOCK / 64][32];
    for (int i = threadIdx.x; i < 4 * 32; i += BLOCK) W1s[i] = W1[i];
    for (int i = threadIdx.x; i < 32 * 32; i += BLOCK) W2s[i] = W2[i];
    if (threadIdx.x < 32) b1s[threadIdx.x] = b1[threadIdx.x];
    __syncthreads();

    int wv = threadIdx.x >> 6, lane = threadIdx.x & 63;
    int n = blockIdx.x * (BLOCK / 64) + wv;
    if (n >= nN) return;

    int el = lane >> 2, comp = lane & 3;        // 16 edge slots x 4 components
    float di = dinv[n];
    int s0 = rowptr[n], s1 = rowptr[n + 1];
    float acc = (el == 0) ? di * di * x[(size_t)n * 4 + comp] : 0.0f;
    int j = s0;
    for (; j + 32 <= s1; j += 32) {
        float2 pa = csr[j + el], pb = csr[j + 16 + el];
        float va = x[(size_t)__float_as_int(pa.x) * 4 + comp];
        float vb = x[(size_t)__float_as_int(pb.x) * 4 + comp];
        acc = fmaf(pa.y, va, acc);
        acc = fmaf(pb.y, vb, acc);
    }
    for (; j + 16 <= s1; j += 16) {
        float2 p = csr[j + el];
        acc = fmaf(p.y, x[(size_t)__float_as_int(p.x) * 4 + comp], acc);
    }
    if (j + el < s1) {
        float2 p = csr[j + el];
        acc = fmaf(p.y, x[(size_t)__float_as_int(p.x) * 4 + comp], acc);
    }
#pragma unroll
    for (int off = 4; off < 64; off <<= 1) acc += __shfl_xor(acc, off);
    float a0 = __shfl(acc, 0), a1 = __shfl(acc, 1), a2c = __shfl(acc, 2), a3 = __shfl(acc, 3);

    int f = lane & 31, e2 = lane >> 5;
    float h = b1s[f];
    h = fmaf(a0, W1s[0 * 32 + f], h);
    h = fmaf(a1, W1s[1 * 32 + f], h);
    h = fmaf(a2c, W1s[2 * 32 + f], h);
    h = fmaf(a3, W1s[3 * 32 + f], h);
    h = fmaxf(h, 0.0f);
    if (lane < 32) hS[wv][f] = h;               // wave-private; DS ops in-order
    float o = 0.0f;
#pragma unroll
    for (int k = 0; k < 16; ++k) {
        int kk = e2 * 16 + k;
        o = fmaf(hS[wv][kk], W2s[kk * 32 + f], o);
    }
    o += __shfl_xor(o, 32);
    if (lane < 32) t_next[(size_t)n * 32 + f] = __float2half(o);
}

// ---------------- fused layer pass (fp16 tables) ----------------

template <bool LAST>
__global__ void layer_pass(const __half* __restrict__ t, const int* __restrict__ rowptr,
                           const float2* __restrict__ csr, const float* __restrict__ dinv,
                           const float* __restrict__ b, const float* __restrict__ W,
                           __half* __restrict__ t_next, float* __restrict__ hout, int nN) {
    __shared__ float Ws[32 * 32];
    __shared__ float hS[BLOCK / 64][32];
    if (!LAST) {
        for (int i = threadIdx.x; i < 32 * 32; i += BLOCK) Ws[i] = W[i];
        __syncthreads();
    }
    int wv = threadIdx.x >> 6, lane = threadIdx.x & 63;
    int e2 = lane >> 5, f = lane & 31;
    int n = blockIdx.x * (BLOCK / 64) + wv;
    if (n >= nN) return;

    float di = dinv[n];
    int s0 = rowptr[n], s1 = rowptr[n + 1];
    float acc = (e2 == 0) ? di * di * __half2float(t[(size_t)n * 32 + f]) : 0.0f;

    int j4 = s0;
    for (; j4 + 16 <= s1; j4 += 16) {
        float2 p[8]; float v[8];
#pragma unroll
        for (int u = 0; u < 8; ++u) p[u] = csr[j4 + 2 * u + e2];
#pragma unroll
        for (int u = 0; u < 8; ++u) v[u] = __half2float(t[(size_t)__float_as_int(p[u].x) * 32 + f]);
#pragma unroll
        for (int u = 0; u < 8; ++u) acc = fmaf(p[u].y, v[u], acc);
    }
    for (; j4 + 4 <= s1; j4 += 4) {
        float2 p[2]; float v[2];
#pragma unroll
        for (int u = 0; u < 2; ++u) p[u] = csr[j4 + 2 * u + e2];
#pragma unroll
        for (int u = 0; u < 2; ++u) v[u] = __half2float(t[(size_t)__float_as_int(p[u].x) * 32 + f]);
#pragma unroll
        for (int u = 0; u < 2; ++u) acc = fmaf(p[u].y, v[u], acc);
    }
    for (int j = j4 + e2; j < s1; j += 2) {
        float2 p = csr[j];
        acc = fmaf(p.y, __half2float(t[(size_t)__float_as_int(p.x) * 32 + f]), acc);
    }

    acc += __shfl_xor(acc, 32);
    float h = acc + b[f];

    if (LAST) {
        if (lane < 32) hout[(size_t)n * 32 + f] = h;
    } else {
        h = fmaxf(h, 0.0f);
        if (lane < 32) hS[wv][f] = h;
        float o = 0.0f;
#pragma unroll
        for (int k = 0; k < 16; ++k) {
            int kk = e2 * 16 + k;
            o = fmaf(hS[wv][kk], Ws[kk * 32 + f], o);
        }
        o += __shfl_xor(o, 32);
        if (lane < 32) t_next[(size_t)n * 32 + f] = __float2half(o);
    }
}

// ---------------- pooling: LDS-privatized (batch sorted) ----------------

#define PB 128   // nodes per block

__global__ void pool_kernel(const float* __restrict__ hout, const int* __restrict__ batch,
                            float* __restrict__ sums, float* __restrict__ cnt, int nN) {
    __shared__ float accS[PB][32];
    __shared__ float cntS[PB];
    __shared__ int g0s;
    int n0 = blockIdx.x * PB;
    for (int i = threadIdx.x; i < PB * 32; i += BLOCK) ((float*)accS)[i] = 0.0f;
    for (int i = threadIdx.x; i < PB; i += BLOCK) cntS[i] = 0.0f;
    if (threadIdx.x == 0) g0s = batch[n0];
    __syncthreads();
    int g0 = g0s;
    int f = threadIdx.x & 31, sub = threadIdx.x >> 5;
    for (int k = 0; k < PB / 8; ++k) {
        int n = n0 + sub + k * 8;
        if (n < nN) {
            int g = batch[n];
            int off = g - g0;
            float v = hout[(size_t)n * 32 + f];
            if (off < PB) {
                atomicAdd(&accS[off][f], v);
                if (f == 0) atomicAdd(&cntS[off], 1.0f);
            } else {   // gap in sorted ids exceeded window (rare) - fall back
                atomicAdd(&sums[(size_t)g * 32 + f], v);
                if (f == 0) atomicAdd(&cnt[g], 1.0f);
            }
        }
    }
    __syncthreads();
    int nLast = min(n0 + PB, nN) - 1;
    int range = min(batch[nLast] - g0, PB - 1);
    for (int s = sub; s <= range; s += 8) {
        atomicAdd(&sums[(size_t)(g0 + s) * 32 + f], accS[s][f]);
        if (f == 0) atomicAdd(&cnt[g0 + s], cntS[s]);
    }
}

// ---------------- classifier ----------------

__global__ void final_kernel(const float* __restrict__ sums, const float* __restrict__ cnt,
                             const float* __restrict__ lin_w, const float* __restrict__ lin_b,
                             float* __restrict__ out, int G) {
    int g = blockIdx.x * blockDim.x + threadIdx.x;
    if (g >= G) return;
    float c = fmaxf(cnt[g], 1.0f);
    float inv = 1.0f / c;
    float l0 = lin_b[0], l1 = lin_b[1], l2 = lin_b[2];
#pragma unroll
    for (int f = 0; f < 32; ++f) {
        float m = sums[g * 32 + f] * inv;
        l0 = fmaf(m, lin_w[f * 3 + 0], l0);
        l1 = fmaf(m, lin_w[f * 3 + 1], l1);
        l2 = fmaf(m, lin_w[f * 3 + 2], l2);
    }
    float mx = fmaxf(l0, fmaxf(l1, l2));
    float e0 = expf(l0 - mx), e1 = expf(l1 - mx), e2 = expf(l2 - mx);
    float s = 1.0f / (e0 + e1 + e2);
    out[g * 3 + 0] = e0 * s;
    out[g * 3 + 1] = e1 * s;
    out[g * 3 + 2] = e2 * s;
}

// ---------------- launch ----------------

extern "C" void kernel_launch(void* const* d_in, const int* in_sizes, int n_in,
                              void* d_out, int out_size, void* d_ws, size_t ws_size,
                              hipStream_t stream) {
    const float* x     = (const float*)d_in[0];
    const int*   ei    = (const int*)d_in[1];
    const float* ew    = (const float*)d_in[2];
    const int*   batch = (const int*)d_in[3];
    const float* W1    = (const float*)d_in[4];
    const float* b1    = (const float*)d_in[5];
    const float* W2    = (const float*)d_in[6];
    const float* b2    = (const float*)d_in[7];
    const float* W3    = (const float*)d_in[8];
    const float* b3    = (const float*)d_in[9];
    const float* lin_w = (const float*)d_in[10];
    const float* lin_b = (const float*)d_in[11];
    float* out = (float*)d_out;

    const int nN = in_sizes[0] / 4;       // 100000
    const int nE = in_sizes[2];           // 2500000
    const int G  = out_size / 3;          // 1000
    const int* row = ei;
    const int* col = ei + nE;
    const int NB = (nN + BLOCK - 1) / BLOCK;

    // workspace layout (byte offsets; 8B alignment for packed/csr)
    char* wsb = (char*)d_ws;
    ull*    packed = (ull*)wsb;                                    // [nN]      0.8 MB
    float2* csr    = (float2*)(packed + nN);                       // [nE]      20 MB
    char*   uReg   = (char*)(csr + nE);                            // 12.8 MB union
    int*    tmp    = (int*)uReg;                                   //   [nE] (build phase)
    float*  hout   = (float*)uReg;                                 //   [nN*32] (after layer3)
    __half* t_a    = (__half*)(uReg + (size_t)nN * 32 * 4);        // [nN*32]   6.4 MB
    __half* t_b    = t_a + (size_t)nN * 32;                        // [nN*32]   6.4 MB
    float*  dinv   = (float*)(t_b + (size_t)nN * 32);              // [nN]
    int*    ecnt   = (int*)(dinv + nN);                            // [nN]
    int*    rowptr = ecnt + nN;                                    // [nN+1]
    int*    blkSum = rowptr + nN + 1;                              // [512]
    int*    blkOff = blkSum + 512;                                 // [512]
    float*  sums   = (float*)(blkOff + 512);                       // [G*32]
    float*  cnt    = sums + (size_t)G * 32;                        // [G]

    const int gN = (nN + BLOCK - 1) / BLOCK;
    const int gE = (nE + BLOCK - 1) / BLOCK;
    const int gW = (nN + (BLOCK / 64) - 1) / (BLOCK / 64);

    // ---- build: 1 atomic/edge ----
    init_kernel<<<gN, BLOCK, 0, stream>>>(packed, sums, cnt, nN, G);
    passA_kernel<<<gE, BLOCK, 0, stream>>>(col, ew, packed, tmp, nE);
    unpack_kernel<<<gN, BLOCK, 0, stream>>>(packed, ecnt, dinv, nN);
    scanA_kernel<<<NB, BLOCK, 0, stream>>>(ecnt, blkSum, nN);
    scanB_kernel<<<1, 512, 0, stream>>>(blkSum, blkOff, rowptr, NB, nN);
    scanC_kernel<<<NB, BLOCK, 0, stream>>>(ecnt, blkOff, rowptr, nN);
    passB_kernel<<<gE, BLOCK, 0, stream>>>(row, col, ew, rowptr, tmp, dinv, csr, nE);

    // ---- layers ----
    layer1_pass<<<gW, BLOCK, 0, stream>>>(x, rowptr, csr, dinv, W1, b1, W2, t_a, nN);
    layer_pass<false><<<gW, BLOCK, 0, stream>>>(t_a, rowptr, csr, dinv, b2, W3, t_b, nullptr, nN);
    layer_pass<true><<<gW, BLOCK, 0, stream>>>(t_b, rowptr, csr, dinv, b3, nullptr, nullptr, hout, nN);

    // ---- pooling + classifier ----
    pool_kernel<<<(nN + PB - 1) / PB, BLOCK, 0, stream>>>(hout, batch, sums, cnt, nN);
    final_kernel<<<(G + BLOCK - 1) / BLOCK, BLOCK, 0, stream>>>(sums, cnt, lin_w, lin_b, out, G);
}